// Round 1
// baseline (33.009 us; speedup 1.0000x reference)
//
#include <hip/hip_runtime.h>
#include <math.h>

// RDF with Gaussian smearing, N=512 points, 400 bins.
// out layout: count[0..399], bins[400..800] (401 vals), rdf[801..1200]
#define NBINS 400
#define NPTS  512
#define RMAXF 13.635f
#define BOXF  (2.0f * RMAXF)

// Kernel 1: pair-parallel windowed Gaussian histogram.
// Each block keeps a private LDS histogram (400 f32), flushes via global atomics.
__global__ __launch_bounds__(256) void rdf_hist(const float* __restrict__ pos,
                                                float* __restrict__ ghist) {
    __shared__ float hist[NBINS];
    for (int b = threadIdx.x; b < NBINS; b += blockDim.x) hist[b] = 0.0f;
    __syncthreads();

    const float width  = RMAXF / 399.0f;           // offsets spacing
    const float inv_w  = 399.0f / RMAXF;
    const float coeff  = -0.5f * inv_w * inv_w;    // -0.5 / width^2
    const float half   = RMAXF;                    // box/2
    const float CUT    = 10.0f;                    // +/-10 sigma window (exp(-50) tail)

    const int total = NPTS * NPTS;
    for (int p = blockIdx.x * blockDim.x + threadIdx.x; p < total;
         p += gridDim.x * blockDim.x) {
        const int i = p >> 9;        // p / 512
        const int j = p & 511;       // p % 512
        float dx = fabsf(pos[3 * i + 0] - pos[3 * j + 0]);
        float dy = fabsf(pos[3 * i + 1] - pos[3 * j + 1]);
        float dz = fabsf(pos[3 * i + 2] - pos[3 * j + 2]);
        // minimum-image fold: if |d| > box/2, d <- box - |d|
        if (dx > half) dx = BOXF - dx;
        if (dy > half) dy = BOXF - dy;
        if (dz > half) dz = BOXF - dz;
        const float dist = sqrtf(dx * dx + dy * dy + dz * dz);
        if (dist <= 0.0f) continue;  // self_mask (diagonal gives exactly 0)

        const float c = dist * inv_w;              // distance in bin-width units
        int b0 = (int)ceilf(c - CUT);
        int b1 = (int)floorf(c + CUT);
        if (b0 < 0) b0 = 0;
        if (b1 > NBINS - 1) b1 = NBINS - 1;
        for (int b = b0; b <= b1; ++b) {
            const float d = dist - (float)b * width;
            atomicAdd(&hist[b], __expf(coeff * d * d));
        }
    }
    __syncthreads();
    for (int b = threadIdx.x; b < NBINS; b += blockDim.x) {
        const float v = hist[b];
        if (v != 0.0f) atomicAdd(&ghist[b], v);
    }
}

// Kernel 2: normalize, write count / bins / rdf.
__global__ __launch_bounds__(512) void rdf_final(const float* __restrict__ ghist,
                                                 float* __restrict__ out) {
    __shared__ float ssum[8];
    const int t = threadIdx.x;
    const float v = (t < NBINS) ? ghist[t] : 0.0f;

    // wave(64) reduce then cross-wave via LDS
    float s = v;
    #pragma unroll
    for (int o = 32; o > 0; o >>= 1) s += __shfl_down(s, o, 64);
    if ((t & 63) == 0) ssum[t >> 6] = s;
    __syncthreads();
    if (t == 0) {
        float tot = 0.0f;
        #pragma unroll
        for (int w = 0; w < 8; ++w) tot += ssum[w];
        ssum[0] = tot;
    }
    __syncthreads();
    const float tot = ssum[0];

    if (t < NBINS) {
        const float cf = v / tot;
        out[t] = cf;                                   // count (normalized)
        // rdf = cf * V / vol_bin = cf * 400^3 / (3b^2+3b+1)  (exact integer form)
        const float denom = (3.0f * t * t + 3.0f * t + 1.0f);
        out[801 + t] = cf * (400.0f * 400.0f * 400.0f) / denom;
    }
    if (t < NBINS + 1) {
        out[NBINS + t] = (float)t * (RMAXF / 400.0f);  // bins = linspace(0, R_MAX, 401)
    }
}

extern "C" void kernel_launch(void* const* d_in, const int* in_sizes, int n_in,
                              void* d_out, int out_size, void* d_ws, size_t ws_size,
                              hipStream_t stream) {
    const float* pos = (const float*)d_in[0];
    float* out = (float*)d_out;
    float* ghist = (float*)d_ws;

    // ws is poisoned (0xAA) once and never re-poisoned: zero it every call.
    hipMemsetAsync(ghist, 0, NBINS * sizeof(float), stream);

    rdf_hist<<<512, 256, 0, stream>>>(pos, ghist);
    rdf_final<<<1, 512, 0, stream>>>(ghist, out);
}

// Round 2
// 32.087 us; speedup vs baseline: 1.0287x; 1.0287x over previous
//
#include <hip/hip_runtime.h>
#include <math.h>

// RDF with Gaussian smearing, N=512 points, 400 bins.
// out layout: count[0..399], bins[400..800] (401 vals), rdf[801..1200]
#define NBINS 400
#define NPTS  512
#define RMAXF 13.635f
#define BOXF  (2.0f * RMAXF)
#define NPART 128   // partial histograms (blocks in kernel 1)

// Kernel 1: pair-parallel windowed Gaussian histogram.
// Each block keeps a private LDS histogram (400 f32) and writes it to its own
// slice of ws with plain coalesced stores (no global atomics, no ws init).
__global__ __launch_bounds__(256) void rdf_hist(const float* __restrict__ pos,
                                                float* __restrict__ part) {
    __shared__ float hist[NBINS];
    for (int b = threadIdx.x; b < NBINS; b += 256) hist[b] = 0.0f;
    __syncthreads();

    const float width = RMAXF / 399.0f;            // offsets spacing
    const float inv_w = 399.0f / RMAXF;
    const float coeff = -0.5f * inv_w * inv_w;     // -0.5 / width^2
    const float half  = RMAXF;                     // box/2
    const float CUT   = 6.5f;                      // +/-6.5 sigma (tail exp(-21) ~ 7e-10)

    const int total = NPTS * NPTS;                 // 262144 pairs
    for (int p = blockIdx.x * 256 + threadIdx.x; p < total; p += NPART * 256) {
        const int i = p >> 9;        // p / 512
        const int j = p & 511;       // p % 512
        float dx = fabsf(pos[3 * i + 0] - pos[3 * j + 0]);
        float dy = fabsf(pos[3 * i + 1] - pos[3 * j + 1]);
        float dz = fabsf(pos[3 * i + 2] - pos[3 * j + 2]);
        // minimum-image fold: if |d| > box/2, d <- box - |d|
        if (dx > half) dx = BOXF - dx;
        if (dy > half) dy = BOXF - dy;
        if (dz > half) dz = BOXF - dz;
        const float dist = sqrtf(dx * dx + dy * dy + dz * dz);
        if (dist <= 0.0f) continue;  // self pairs (diagonal gives exactly 0)

        const float c = dist * inv_w;              // distance in bin-width units
        int b0 = (int)ceilf(c - CUT);
        int b1 = (int)floorf(c + CUT);
        if (b0 < 0) b0 = 0;
        if (b1 > NBINS - 1) b1 = NBINS - 1;
        for (int b = b0; b <= b1; ++b) {
            const float d = dist - (float)b * width;
            atomicAdd(&hist[b], __expf(coeff * d * d));
        }
    }
    __syncthreads();
    for (int b = threadIdx.x; b < NBINS; b += 256)
        part[blockIdx.x * NBINS + b] = hist[b];
}

// Kernel 2: reduce partials, normalize, write count / bins / rdf.
__global__ __launch_bounds__(512) void rdf_final(const float* __restrict__ part,
                                                 float* __restrict__ out) {
    __shared__ float ssum[8];
    const int t = threadIdx.x;

    float v = 0.0f;
    if (t < NBINS) {
        #pragma unroll 8
        for (int p = 0; p < NPART; ++p) v += part[p * NBINS + t];
    }

    // total = sum over bins: wave(64) reduce then cross-wave via LDS
    float s = v;
    #pragma unroll
    for (int o = 32; o > 0; o >>= 1) s += __shfl_down(s, o, 64);
    if ((t & 63) == 0) ssum[t >> 6] = s;
    __syncthreads();
    if (t == 0) {
        float tot = 0.0f;
        #pragma unroll
        for (int w = 0; w < 8; ++w) tot += ssum[w];
        ssum[0] = tot;
    }
    __syncthreads();
    const float tot = ssum[0];

    if (t < NBINS) {
        const float cf = v / tot;
        out[t] = cf;                                   // count (normalized)
        // rdf = cf * V / vol_bin = cf * 400^3 / (3b^2+3b+1)  (exact integer form)
        const float denom = (3.0f * t * t + 3.0f * t + 1.0f);
        out[801 + t] = cf * (400.0f * 400.0f * 400.0f) / denom;
    }
    if (t < NBINS + 1) {
        out[NBINS + t] = (float)t * (RMAXF / 400.0f);  // bins = linspace(0, R_MAX, 401)
    }
}

extern "C" void kernel_launch(void* const* d_in, const int* in_sizes, int n_in,
                              void* d_out, int out_size, void* d_ws, size_t ws_size,
                              hipStream_t stream) {
    const float* pos = (const float*)d_in[0];
    float* out = (float*)d_out;
    float* part = (float*)d_ws;   // NPART * NBINS floats, fully overwritten each call

    rdf_hist<<<NPART, 256, 0, stream>>>(pos, part);
    rdf_final<<<1, 512, 0, stream>>>(part, out);
}